// Round 6
// baseline (2316.256 us; speedup 1.0000x reference)
//
#include <hip/hip_runtime.h>

// ============================================================================
// VQ-VAE forward, MI355X fp32. Internal layout NHWC; outputs NCHW.
// B=4096. x(4096,1,28,28) -> h1(4096,14,14,32) -> h2(4096,7,7,64)
//   -> z -> VQ(512 codes, D=64) -> d0 -> d1(4096,14,14,32) -> recon.
// VQ argmin reproduces np fp32 semantics exactly:
//   dist = fl( fl(SZ + SC_k) - 2*dot(z,c_k) ), SZ/SC via numpy pairwise-8,
//   dot via sequential-K fma (BLAS order), first-min-wins tie break.
// R2: unrolled tap loop -> 256-VGPR cap -> scratch spill -> 12 GB HBM.
// R3: barrier-per-slice weight staging -> global latency on critical path.
// R4: k2/k6 were LDS-read bound -> s_load weights + polyphase LDS x + big
//   register tiles, barrier-free K loops.
// R5 lesson: k4_vq was (a) LDS-capped at 2 blocks/CU (66KB tile) and
//   (b) latency-bound on a single sequential 64-fma chain per code.
//   Fix: k-unroll x4 (4 independent chains, per-code order unchanged),
//   no LDS at all (direct strided f4 loads; L1 absorbs), and the d0 1x1
//   conv fused into the epilogue (writes d0 in-place over z slice).
// Workspace (floats): h1/d1 @0 (25,690,112) | h2 @25,690,112 (12,845,056)
//   | z/d0 @38,535,168 (12,845,056) | cn @51,380,224 (512) | loss @51,380,736
// Out (floats): recon@0, z@3,211,264, z_q@16,056,320, loss@28,901,376,
//   idx@28,901,377 (200,704)
// ============================================================================

#define NB 4096

__device__ __forceinline__ float4 f4fma(float s, float4 w, float4 a) {
  a.x = fmaf(s, w.x, a.x); a.y = fmaf(s, w.y, a.y);
  a.z = fmaf(s, w.z, a.z); a.w = fmaf(s, w.w, a.w);
  return a;
}
__device__ __forceinline__ float4 f4relu(float4 a) {
  a.x = fmaxf(a.x, 0.f); a.y = fmaxf(a.y, 0.f);
  a.z = fmaxf(a.z, 0.f); a.w = fmaxf(a.w, 0.f);
  return a;
}
__device__ __forceinline__ float4 f4addrn(float4 a, float4 b) {
  a.x = __fadd_rn(a.x, b.x); a.y = __fadd_rn(a.y, b.y);
  a.z = __fadd_rn(a.z, b.z); a.w = __fadd_rn(a.w, b.w);
  return a;
}

// numpy pairwise-8 sum of squares over 64 contiguous values
__device__ __forceinline__ float np_sumsq64(const float* v) {
  float r[8];
#pragma unroll
  for (int j = 0; j < 8; ++j) r[j] = __fmul_rn(v[j], v[j]);
#pragma unroll
  for (int i = 8; i < 64; i += 8)
#pragma unroll
    for (int j = 0; j < 8; ++j) r[j] = __fadd_rn(r[j], __fmul_rn(v[i + j], v[i + j]));
  return __fadd_rn(__fadd_rn(__fadd_rn(r[0], r[1]), __fadd_rn(r[2], r[3])),
                   __fadd_rn(__fadd_rn(r[4], r[5]), __fadd_rn(r[6], r[7])));
}

// ---- K0: codebook norms (numpy-order) + zero loss accumulator --------------
__global__ __launch_bounds__(256) void k0_init(const float* __restrict__ cb,
                                               float* __restrict__ cn,
                                               float* __restrict__ loss) {
  int t = threadIdx.x;
  if (t == 0) *loss = 0.f;
  for (int k = t; k < 512; k += 256) cn[k] = np_sumsq64(&cb[k * 64]);
}

// ---- K1: conv1 4x4 s2 p1, 1->32, bias-after, ReLU. out h1 NHWC -------------
__global__ __launch_bounds__(256) void k1_conv1(const float* __restrict__ x,
                                                const float* __restrict__ w1,
                                                const float* __restrict__ b1,
                                                float* __restrict__ h1) {
  __shared__ float xs[784];
  __shared__ float wl[512];
  __shared__ float bs[32];
  int n = blockIdx.x, t = threadIdx.x;
  for (int j = t; j < 784; j += 256) xs[j] = x[n * 784 + j];
  for (int j = t; j < 512; j += 256) wl[j] = w1[j];
  if (t < 32) bs[t] = b1[t];
  __syncthreads();
  int c = t & 31, pg = t >> 5;
  for (int s = pg; s < 196; s += 8) {
    int oh = s / 14, ow = s % 14;
    float acc = 0.f;
#pragma unroll
    for (int kh = 0; kh < 4; ++kh) {
      int ih = 2 * oh - 1 + kh;
      if (ih < 0 || ih >= 28) continue;
#pragma unroll
      for (int kw = 0; kw < 4; ++kw) {
        int iw = 2 * ow - 1 + kw;
        if (iw < 0 || iw >= 28) continue;
        acc = fmaf(xs[ih * 28 + iw], wl[(kh * 4 + kw) * 32 + c], acc);
      }
    }
    acc = __fadd_rn(acc, bs[c]);
    h1[(n * 196 + s) * 32 + c] = fmaxf(acc, 0.f);
  }
}

// ---- K2: conv2 4x4 s2 p1, 32->64, bias-after, ReLU. NHWC -------------------
// 2 img/block. x in padded polyphase LDS grid [c4:8][row:16][par:2][col8:8]
// (f4 chunks, img stride 2049). Weights via wave-uniform s_load (16 co/wave).
// Thread: 2 positions x 16 co. K-loop barrier-free.
__global__ __launch_bounds__(256) void k2_conv2(const float* __restrict__ h1,
                                                const float* __restrict__ w2,
                                                const float* __restrict__ b2,
                                                float* __restrict__ h2) {
  __shared__ float4 xs4[2 * 2049];
  int nb = blockIdx.x, t = threadIdx.x;
  size_t n0 = (size_t)nb * 2;
  for (int j = t; j < 4098; j += 256) xs4[j] = make_float4(0.f, 0.f, 0.f, 0.f);
  __syncthreads();
  for (int j = t; j < 1568; j += 256) {
    int p = j >> 3, c4 = j & 7;
    int ihp = p / 14 + 1, iwp = p % 14 + 1;
    int chunk = (c4 * 16 + ihp) * 16 + (iwp & 1) * 8 + (iwp >> 1);
    xs4[chunk] = *(const float4*)(h1 + n0 * 6272 + p * 32 + c4 * 4);
    xs4[2049 + chunk] = *(const float4*)(h1 + (n0 + 1) * 6272 + p * 32 + c4 * 4);
  }
  __syncthreads();
  int l = t & 63;
  int co0 = __builtin_amdgcn_readfirstlane((t >> 6) * 16);
  int img = l >> 5, pt = l & 31;
  int oh0 = pt >> 3, ow = pt & 7;
  int imgoff = img * 2049;
  bool v0 = (ow < 7);
  bool v1 = (ow < 7) && (oh0 + 4 < 7);
  float4 A0[4], A1[4];
#pragma unroll
  for (int g = 0; g < 4; ++g) { A0[g] = make_float4(0.f, 0.f, 0.f, 0.f); A1[g] = A0[g]; }
#pragma unroll 1
  for (int kk = 0; kk < 16; ++kk) {
    int kh = kk >> 2, kw = kk & 3;
    int cc = 2 * ow + kw; if (cc > 15) cc = 15;
    int off = (cc & 1) * 8 + (cc >> 1);
    int rc0 = 2 * oh0 + kh;
    int rc1 = rc0 + 8; if (rc1 > 15) rc1 = 15;
    int b0 = imgoff + rc0 * 16 + off;
    int b1 = imgoff + rc1 * 16 + off;
    int wb = __builtin_amdgcn_readfirstlane(kk * 2048 + co0);
#pragma unroll 2
    for (int c4 = 0; c4 < 8; ++c4) {
      float4 x0 = xs4[b0 + c4 * 256];
      float4 x1 = xs4[b1 + c4 * 256];
      float xa0[4] = {x0.x, x0.y, x0.z, x0.w};
      float xa1[4] = {x1.x, x1.y, x1.z, x1.w};
      const float* wk = w2 + wb + c4 * 256;
#pragma unroll
      for (int j = 0; j < 4; ++j) {
#pragma unroll
        for (int g = 0; g < 4; ++g) {
          float4 wv4;
          wv4.x = wk[j * 64 + g * 4 + 0]; wv4.y = wk[j * 64 + g * 4 + 1];
          wv4.z = wk[j * 64 + g * 4 + 2]; wv4.w = wk[j * 64 + g * 4 + 3];
          A0[g] = f4fma(xa0[j], wv4, A0[g]);
          A1[g] = f4fma(xa1[j], wv4, A1[g]);
        }
      }
    }
  }
  float4 bias[4];
#pragma unroll
  for (int g = 0; g < 4; ++g) bias[g] = *(const float4*)&b2[co0 + g * 4];
  if (v0) {
    size_t ob = ((n0 + img) * 49 + oh0 * 7 + ow) * 64 + co0;
#pragma unroll
    for (int g = 0; g < 4; ++g)
      *(float4*)&h2[ob + g * 4] = f4relu(f4addrn(A0[g], bias[g]));
  }
  if (v1) {
    size_t ob = ((n0 + img) * 49 + (oh0 + 4) * 7 + ow) * 64 + co0;
#pragma unroll
    for (int g = 0; g < 4; ++g)
      *(float4*)&h2[ob + g * 4] = f4relu(f4addrn(A1[g], bias[g]));
  }
}

// ---- K_pw: 1x1 conv 64->64, bias-after (no act). NHWC, no LDS --------------
// Per-co accumulation order over ci identical to previous rounds (np-safe).
__global__ __launch_bounds__(256) void k_pw(const float* __restrict__ xin,
                                            const float* __restrict__ w,     // [ci][co]
                                            const float* __restrict__ bias,
                                            float* __restrict__ yout) {
  size_t m = (size_t)blockIdx.x * 256 + threadIdx.x;
  const float* xp = xin + m * 64;
  float xr[64];
#pragma unroll
  for (int c4 = 0; c4 < 16; ++c4) {
    float4 v = *(const float4*)(xp + c4 * 4);
    xr[c4 * 4 + 0] = v.x; xr[c4 * 4 + 1] = v.y;
    xr[c4 * 4 + 2] = v.z; xr[c4 * 4 + 3] = v.w;
  }
  float4 A[16];
#pragma unroll
  for (int g = 0; g < 16; ++g) A[g] = make_float4(0.f, 0.f, 0.f, 0.f);
#pragma unroll 1
  for (int ci = 0; ci < 64; ++ci) {
    float xv = xr[ci];
    const float* wr = w + ci * 64;
#pragma unroll
    for (int g = 0; g < 16; ++g)
      A[g] = f4fma(xv, *(const float4*)(wr + g * 4), A[g]);
  }
  float* yp = yout + m * 64;
#pragma unroll
  for (int g = 0; g < 16; ++g)
    *(float4*)(yp + g * 4) = f4addrn(A[g], *(const float4*)(bias + g * 4));
}

// ---- K4: VQ + fused d0 1x1. no LDS, no barriers ----------------------------
// Reads z slice, writes z NCHW, idx, z_q NCHW, loss, and d0 (= zq@dw0+db0)
// IN-PLACE over the z slice (each thread owns its row).
__global__ __launch_bounds__(256) void k4_vq(float* __restrict__ zbuf,
                                             const float* __restrict__ cb,
                                             const float* __restrict__ cn,
                                             const float* __restrict__ dw0,
                                             const float* __restrict__ db0,
                                             float* __restrict__ outz,
                                             float* __restrict__ outzq,
                                             float* __restrict__ outidx,
                                             float* __restrict__ loss) {
  int t = threadIdx.x;
  size_t m = (size_t)blockIdx.x * 256 + t;
  const float* zp = zbuf + m * 64;
  float zr[64];
#pragma unroll
  for (int c4 = 0; c4 < 16; ++c4) {
    float4 v = *(const float4*)(zp + c4 * 4);
    zr[c4 * 4 + 0] = v.x; zr[c4 * 4 + 1] = v.y;
    zr[c4 * 4 + 2] = v.z; zr[c4 * 4 + 3] = v.w;
  }
  unsigned n = (unsigned)(m / 49u), sp = (unsigned)(m % 49u);
  float* zob = outz + (size_t)n * 3136 + sp;
#pragma unroll
  for (int ci = 0; ci < 64; ++ci) zob[ci * 49] = zr[ci];
  // np-exact argmin: dist = fl( fl(SZ + SC_k) - 2*dot ), first-min-wins.
  // k unrolled x4: 4 independent per-code chains (per-code order unchanged).
  float sz = np_sumsq64(zr);
  float minv = 3.4e38f; int mini = 0;
#pragma unroll 1
  for (int k = 0; k < 512; k += 4) {
    const float* cp = cb + (size_t)k * 64;
    float d0_ = 0.f, d1_ = 0.f, d2_ = 0.f, d3_ = 0.f;
#pragma unroll
    for (int ci = 0; ci < 64; ci += 4) {
      float4 a = *(const float4*)(cp + ci);
      float4 b = *(const float4*)(cp + 64 + ci);
      float4 c = *(const float4*)(cp + 128 + ci);
      float4 e = *(const float4*)(cp + 192 + ci);
      d0_ = fmaf(zr[ci], a.x, d0_); d0_ = fmaf(zr[ci + 1], a.y, d0_);
      d0_ = fmaf(zr[ci + 2], a.z, d0_); d0_ = fmaf(zr[ci + 3], a.w, d0_);
      d1_ = fmaf(zr[ci], b.x, d1_); d1_ = fmaf(zr[ci + 1], b.y, d1_);
      d1_ = fmaf(zr[ci + 2], b.z, d1_); d1_ = fmaf(zr[ci + 3], b.w, d1_);
      d2_ = fmaf(zr[ci], c.x, d2_); d2_ = fmaf(zr[ci + 1], c.y, d2_);
      d2_ = fmaf(zr[ci + 2], c.z, d2_); d2_ = fmaf(zr[ci + 3], c.w, d2_);
      d3_ = fmaf(zr[ci], e.x, d3_); d3_ = fmaf(zr[ci + 1], e.y, d3_);
      d3_ = fmaf(zr[ci + 2], e.z, d3_); d3_ = fmaf(zr[ci + 3], e.w, d3_);
    }
    float q0 = __fsub_rn(__fadd_rn(sz, cn[k + 0]), __fmul_rn(2.f, d0_));
    float q1 = __fsub_rn(__fadd_rn(sz, cn[k + 1]), __fmul_rn(2.f, d1_));
    float q2 = __fsub_rn(__fadd_rn(sz, cn[k + 2]), __fmul_rn(2.f, d2_));
    float q3 = __fsub_rn(__fadd_rn(sz, cn[k + 3]), __fmul_rn(2.f, d3_));
    if (q0 < minv) { minv = q0; mini = k; }
    if (q1 < minv) { minv = q1; mini = k + 1; }
    if (q2 < minv) { minv = q2; mini = k + 2; }
    if (q3 < minv) { minv = q3; mini = k + 3; }
  }
  outidx[m] = (float)mini;
  // Epilogue: zq scatter + loss + fused d0 = zq @ dw0 + db0.
  float* qob = outzq + (size_t)n * 3136 + sp;
  const float* qrow = cb + (size_t)mini * 64;
  float lsum = 0.f;
  float4 A[16];
#pragma unroll
  for (int g = 0; g < 16; ++g) A[g] = make_float4(0.f, 0.f, 0.f, 0.f);
#pragma unroll
  for (int c4 = 0; c4 < 16; ++c4) {
    float4 q4 = *(const float4*)(qrow + c4 * 4);
    qob[(c4 * 4 + 0) * 49] = q4.x; qob[(c4 * 4 + 1) * 49] = q4.y;
    qob[(c4 * 4 + 2) * 49] = q4.z; qob[(c4 * 4 + 3) * 49] = q4.w;
    float e0 = q4.x - zr[c4 * 4 + 0], e1 = q4.y - zr[c4 * 4 + 1];
    float e2 = q4.z - zr[c4 * 4 + 2], e3 = q4.w - zr[c4 * 4 + 3];
    lsum = fmaf(e0, e0, lsum); lsum = fmaf(e1, e1, lsum);
    lsum = fmaf(e2, e2, lsum); lsum = fmaf(e3, e3, lsum);
    float qa[4] = {q4.x, q4.y, q4.z, q4.w};
#pragma unroll
    for (int j = 0; j < 4; ++j) {
      const float* wr = dw0 + (c4 * 4 + j) * 64;
#pragma unroll
      for (int g = 0; g < 16; ++g)
        A[g] = f4fma(qa[j], *(const float4*)(wr + g * 4), A[g]);
    }
  }
#pragma unroll
  for (int off = 32; off > 0; off >>= 1) lsum += __shfl_down(lsum, off);
  if ((t & 63) == 0) atomicAdd(loss, lsum);
  float* dst = zbuf + m * 64;
#pragma unroll
  for (int g = 0; g < 16; ++g)
    *(float4*)(dst + g * 4) = f4addrn(A[g], *(const float4*)(db0 + g * 4));
}

// ---- K4b: finalize loss ----------------------------------------------------
__global__ __launch_bounds__(64) void k_lossfin(const float* __restrict__ loss,
                                                float* __restrict__ out) {
  if (threadIdx.x == 0) out[0] = loss[0] * (1.25f / 12845056.f);
}

// ---- K6: deconv1 4x4 s2 p2 (lhs_dilation), 64->32, ReLU. NHWC --------------
// Wave = phase (ra=oh&1, rb=ow&1); x staged ONCE in padded grid
// [c4:16][row:9][col:9] f4 chunks (img stride 1297). Weights via s_load.
// Thread: 2 positions x 32 co. K-loop barrier-free, no per-phase restage.
__global__ __launch_bounds__(256) void k6_deconv1(const float* __restrict__ d0,
                                                  const float* __restrict__ dw1,
                                                  const float* __restrict__ db1,
                                                  float* __restrict__ d1) {
  __shared__ float4 xs4[2 * 1297];
  int nb = blockIdx.x, t = threadIdx.x;
  size_t n0 = (size_t)nb * 2;
  for (int j = t; j < 2594; j += 256) xs4[j] = make_float4(0.f, 0.f, 0.f, 0.f);
  __syncthreads();
  for (int j = t; j < 784; j += 256) {
    int p = j >> 4, c4 = j & 15;
    int chunk = c4 * 81 + (p / 7 + 1) * 9 + (p % 7 + 1);
    xs4[chunk] = *(const float4*)(d0 + n0 * 3136 + p * 64 + c4 * 4);
    xs4[1297 + chunk] = *(const float4*)(d0 + (n0 + 1) * 3136 + p * 64 + c4 * 4);
  }
  __syncthreads();
  int l = t & 63;
  int ph = __builtin_amdgcn_readfirstlane(t >> 6);
  int ra = ph >> 1, rb = ph & 1;
  int img = l >> 5, pt = l & 31;
  bool v1 = (pt + 32 < 49);
  int p1 = v1 ? pt + 32 : 48;
  int mh0 = pt / 7, mw0 = pt % 7;
  int mh1 = p1 / 7, mw1 = p1 % 7;
  int imgoff = img * 1297;
  float4 A0[8], A1[8];
#pragma unroll
  for (int g = 0; g < 8; ++g) { A0[g] = make_float4(0.f, 0.f, 0.f, 0.f); A1[g] = A0[g]; }
#pragma unroll 1
  for (int tap = 0; tap < 4; ++tap) {
    int th = tap >> 1, tw = tap & 1;
    int kh = 2 * th + ra, kw = 2 * tw + rb;
    int b0 = imgoff + (mh0 + th + ra) * 9 + (mw0 + tw + rb);
    int b1 = imgoff + (mh1 + th + ra) * 9 + (mw1 + tw + rb);
    int wb = __builtin_amdgcn_readfirstlane((kh * 4 + kw) * 2048);
#pragma unroll 1
    for (int c4 = 0; c4 < 16; ++c4) {
      float4 x0 = xs4[b0 + c4 * 81];
      float4 x1 = xs4[b1 + c4 * 81];
      float xa0[4] = {x0.x, x0.y, x0.z, x0.w};
      float xa1[4] = {x1.x, x1.y, x1.z, x1.w};
      const float* wk = dw1 + wb + c4 * 128;
#pragma unroll
      for (int j = 0; j < 4; ++j) {
#pragma unroll
        for (int g = 0; g < 8; ++g) {
          float4 wv4;
          wv4.x = wk[j * 32 + g * 4 + 0]; wv4.y = wk[j * 32 + g * 4 + 1];
          wv4.z = wk[j * 32 + g * 4 + 2]; wv4.w = wk[j * 32 + g * 4 + 3];
          A0[g] = f4fma(xa0[j], wv4, A0[g]);
          A1[g] = f4fma(xa1[j], wv4, A1[g]);
        }
      }
    }
  }
  int oh0 = 2 * mh0 + ra, ow0 = 2 * mw0 + rb;
  size_t ob0 = ((n0 + img) * 196 + (size_t)(oh0 * 14 + ow0)) * 32;
#pragma unroll
  for (int g = 0; g < 8; ++g) {
    float4 bg = *(const float4*)&db1[g * 4];
    *(float4*)&d1[ob0 + g * 4] = f4relu(f4addrn(A0[g], bg));
  }
  if (v1) {
    int oh1 = 2 * mh1 + ra, ow1 = 2 * mw1 + rb;
    size_t ob1 = ((n0 + img) * 196 + (size_t)(oh1 * 14 + ow1)) * 32;
#pragma unroll
    for (int g = 0; g < 8; ++g) {
      float4 bg = *(const float4*)&db1[g * 4];
      *(float4*)&d1[ob1 + g * 4] = f4relu(f4addrn(A1[g], bg));
    }
  }
}

// ---- K7: deconv2 4x4 s2 p2, 32->1, sigmoid -> recon NCHW -------------------
__global__ __launch_bounds__(256) void k7_deconv2(const float* __restrict__ d1,
                                                  const float* __restrict__ dw2,
                                                  const float* __restrict__ db2,
                                                  float* __restrict__ recon) {
  __shared__ float xs[196 * 36];
  __shared__ float wl[512];
  int n = blockIdx.x, t = threadIdx.x;
  for (int j = t; j < 6272; j += 256) xs[(j >> 5) * 36 + (j & 31)] = d1[(size_t)n * 6272 + j];
  for (int j = t; j < 512; j += 256) wl[j] = dw2[j];
  __syncthreads();
  float bias = db2[0];
  for (int j = t; j < 392; j += 256) {
    int ra = j / 196, rem = j % 196;
    int mh = rem / 14, mw = rem % 14;
    float acc0 = bias, acc1 = bias;
    bool vm = (mw >= 1), vp = (mw + 1 < 14);
#pragma unroll
    for (int th = 0; th < 2; ++th) {
      int ih = mh + th - 1 + ra;
      if (ih < 0 || ih >= 14) continue;
      int kh = 2 * th + ra;
#pragma unroll
      for (int ci = 0; ci < 32; ci += 4) {
        float4 z4 = make_float4(0.f, 0.f, 0.f, 0.f);
        float4 xm = vm ? *(float4*)&xs[(ih * 14 + mw - 1) * 36 + ci] : z4;
        float4 x0 = *(float4*)&xs[(ih * 14 + mw) * 36 + ci];
        float4 xp = vp ? *(float4*)&xs[(ih * 14 + mw + 1) * 36 + ci] : z4;
        float4 wk0 = *(float4*)&wl[(kh * 4 + 0) * 32 + ci];
        float4 wk1 = *(float4*)&wl[(kh * 4 + 1) * 32 + ci];
        float4 wk2 = *(float4*)&wl[(kh * 4 + 2) * 32 + ci];
        float4 wk3 = *(float4*)&wl[(kh * 4 + 3) * 32 + ci];
        acc0 = fmaf(xm.x, wk0.x, acc0); acc0 = fmaf(xm.y, wk0.y, acc0);
        acc0 = fmaf(xm.z, wk0.z, acc0); acc0 = fmaf(xm.w, wk0.w, acc0);
        acc0 = fmaf(x0.x, wk2.x, acc0); acc0 = fmaf(x0.y, wk2.y, acc0);
        acc0 = fmaf(x0.z, wk2.z, acc0); acc0 = fmaf(x0.w, wk2.w, acc0);
        acc1 = fmaf(x0.x, wk1.x, acc1); acc1 = fmaf(x0.y, wk1.y, acc1);
        acc1 = fmaf(x0.z, wk1.z, acc1); acc1 = fmaf(x0.w, wk1.w, acc1);
        acc1 = fmaf(xp.x, wk3.x, acc1); acc1 = fmaf(xp.y, wk3.y, acc1);
        acc1 = fmaf(xp.z, wk3.z, acc1); acc1 = fmaf(xp.w, wk3.w, acc1);
      }
    }
    float r0 = 1.f / (1.f + __expf(-acc0));
    float r1 = 1.f / (1.f + __expf(-acc1));
    int oh = 2 * mh + ra;
    *(float2*)&recon[(size_t)n * 784 + oh * 28 + 2 * mw] = make_float2(r0, r1);
  }
}

extern "C" void kernel_launch(void* const* d_in, const int* in_sizes, int n_in,
                              void* d_out, int out_size, void* d_ws, size_t ws_size,
                              hipStream_t stream) {
  const float* x   = (const float*)d_in[0];
  const float* w1  = (const float*)d_in[1];
  const float* b1  = (const float*)d_in[2];
  const float* w2  = (const float*)d_in[3];
  const float* b2  = (const float*)d_in[4];
  const float* w3  = (const float*)d_in[5];
  const float* b3  = (const float*)d_in[6];
  const float* cb  = (const float*)d_in[7];
  const float* dw0 = (const float*)d_in[8];
  const float* db0 = (const float*)d_in[9];
  const float* dw1 = (const float*)d_in[10];
  const float* db1 = (const float*)d_in[11];
  const float* dw2 = (const float*)d_in[12];
  const float* db2 = (const float*)d_in[13];
  float* out = (float*)d_out;
  float* ws  = (float*)d_ws;

  float* h1   = ws;                 // 25,690,112 (reused as d1)
  float* h2   = ws + 25690112;      // 12,845,056
  float* zb   = ws + 38535168;      // 12,845,056 z, then d0 in-place
  float* cn   = ws + 51380224;      // 512
  float* loss = ws + 51380736;      // 1

  float* recon   = out;
  float* zout    = out + 3211264;
  float* zqout   = out + 16056320;
  float* lossout = out + 28901376;
  float* idxout  = out + 28901377;

  k0_init<<<1, 256, 0, stream>>>(cb, cn, loss);
  k1_conv1<<<NB, 256, 0, stream>>>(x, w1, b1, h1);
  k2_conv2<<<NB / 2, 256, 0, stream>>>(h1, w2, b2, h2);
  k_pw<<<784, 256, 0, stream>>>(h2, w3, b3, zb);                 // z = h2 @ w3 + b3
  k4_vq<<<784, 256, 0, stream>>>(zb, cb, cn, dw0, db0,           // VQ + fused d0
                                 zout, zqout, idxout, loss);
  k_lossfin<<<1, 64, 0, stream>>>(loss, lossout);
  k6_deconv1<<<NB / 2, 256, 0, stream>>>(zb, dw1, db1, h1);
  k7_deconv2<<<NB, 256, 0, stream>>>(h1, dw2, db2, recon);
}

// Round 7
// 1300.394 us; speedup vs baseline: 1.7812x; 1.7812x over previous
//
#include <hip/hip_runtime.h>

// ============================================================================
// VQ-VAE forward, MI355X fp32. Internal layout NHWC; outputs NCHW.
// B=4096. x(4096,1,28,28) -> h1(4096,14,14,32) -> h2(4096,7,7,64)
//   -> z -> VQ(512 codes, D=64) -> d0 -> d1(4096,14,14,32) -> recon.
// VQ argmin reproduces np fp32 semantics exactly:
//   dist = fl( fl(SZ + SC_k) - 2*dot(z,c_k) ), SZ/SC via numpy pairwise-8,
//   dot via sequential-K fma (BLAS order), first-min-wins tie break.
// R2: unrolled tap loop -> 256-VGPR cap -> scratch spill -> 12 GB HBM.
// R3: barrier-per-slice weight staging -> global latency on critical path.
// R4: k2/k6 were LDS-read bound -> s_load weights + polyphase LDS x + big
//   register tiles, barrier-free K loops.
// R5: k4 latency-bound on one sequential 64-fma chain per code.
// R6 lesson (REVERTED): dropping LDS staging for per-thread-contiguous
//   global access (256B wave stride) is catastrophic: 64 line-req/instr,
//   2x write amplification, k4 452->1468us. ALWAYS stage coalesced via LDS.
// R7: R5 structure + k-unroll x4 ONLY (4 independent per-code chains;
//   per-code ci order and k-order compares unchanged -> np-exact).
// Workspace (floats): h1/d1 @0 (25,690,112) | h2/zq @25,690,112 (12,845,056)
//   | z/d0 @38,535,168 (12,845,056) | cn @51,380,224 (512) | loss @51,380,736
// Out (floats): recon@0, z@3,211,264, z_q@16,056,320, loss@28,901,376,
//   idx@28,901,377 (200,704)
// ============================================================================

#define NB 4096

__device__ __forceinline__ float4 f4fma(float s, float4 w, float4 a) {
  a.x = fmaf(s, w.x, a.x); a.y = fmaf(s, w.y, a.y);
  a.z = fmaf(s, w.z, a.z); a.w = fmaf(s, w.w, a.w);
  return a;
}
__device__ __forceinline__ float4 f4relu(float4 a) {
  a.x = fmaxf(a.x, 0.f); a.y = fmaxf(a.y, 0.f);
  a.z = fmaxf(a.z, 0.f); a.w = fmaxf(a.w, 0.f);
  return a;
}
__device__ __forceinline__ float4 f4addrn(float4 a, float4 b) {
  a.x = __fadd_rn(a.x, b.x); a.y = __fadd_rn(a.y, b.y);
  a.z = __fadd_rn(a.z, b.z); a.w = __fadd_rn(a.w, b.w);
  return a;
}

// numpy pairwise-8 sum of squares over 64 contiguous values
__device__ __forceinline__ float np_sumsq64(const float* v) {
  float r[8];
#pragma unroll
  for (int j = 0; j < 8; ++j) r[j] = __fmul_rn(v[j], v[j]);
#pragma unroll
  for (int i = 8; i < 64; i += 8)
#pragma unroll
    for (int j = 0; j < 8; ++j) r[j] = __fadd_rn(r[j], __fmul_rn(v[i + j], v[i + j]));
  return __fadd_rn(__fadd_rn(__fadd_rn(r[0], r[1]), __fadd_rn(r[2], r[3])),
                   __fadd_rn(__fadd_rn(r[4], r[5]), __fadd_rn(r[6], r[7])));
}

// ---- K0: codebook norms (numpy-order) + zero loss accumulator --------------
__global__ __launch_bounds__(256) void k0_init(const float* __restrict__ cb,
                                               float* __restrict__ cn,
                                               float* __restrict__ loss) {
  int t = threadIdx.x;
  if (t == 0) *loss = 0.f;
  for (int k = t; k < 512; k += 256) cn[k] = np_sumsq64(&cb[k * 64]);
}

// ---- K1: conv1 4x4 s2 p1, 1->32, bias-after, ReLU. out h1 NHWC -------------
__global__ __launch_bounds__(256) void k1_conv1(const float* __restrict__ x,
                                                const float* __restrict__ w1,
                                                const float* __restrict__ b1,
                                                float* __restrict__ h1) {
  __shared__ float xs[784];
  __shared__ float wl[512];
  __shared__ float bs[32];
  int n = blockIdx.x, t = threadIdx.x;
  for (int j = t; j < 784; j += 256) xs[j] = x[n * 784 + j];
  for (int j = t; j < 512; j += 256) wl[j] = w1[j];
  if (t < 32) bs[t] = b1[t];
  __syncthreads();
  int c = t & 31, pg = t >> 5;
  for (int s = pg; s < 196; s += 8) {
    int oh = s / 14, ow = s % 14;
    float acc = 0.f;
#pragma unroll
    for (int kh = 0; kh < 4; ++kh) {
      int ih = 2 * oh - 1 + kh;
      if (ih < 0 || ih >= 28) continue;
#pragma unroll
      for (int kw = 0; kw < 4; ++kw) {
        int iw = 2 * ow - 1 + kw;
        if (iw < 0 || iw >= 28) continue;
        acc = fmaf(xs[ih * 28 + iw], wl[(kh * 4 + kw) * 32 + c], acc);
      }
    }
    acc = __fadd_rn(acc, bs[c]);
    h1[(n * 196 + s) * 32 + c] = fmaxf(acc, 0.f);
  }
}

// ---- K2: conv2 4x4 s2 p1, 32->64, bias-after, ReLU. NHWC -------------------
// 2 img/block. x in padded polyphase LDS grid [c4:8][row:16][par:2][col8:8]
// (f4 chunks, img stride 2049). Weights via wave-uniform s_load (16 co/wave).
// Thread: 2 positions x 16 co. K-loop barrier-free.
__global__ __launch_bounds__(256) void k2_conv2(const float* __restrict__ h1,
                                                const float* __restrict__ w2,
                                                const float* __restrict__ b2,
                                                float* __restrict__ h2) {
  __shared__ float4 xs4[2 * 2049];
  int nb = blockIdx.x, t = threadIdx.x;
  size_t n0 = (size_t)nb * 2;
  for (int j = t; j < 4098; j += 256) xs4[j] = make_float4(0.f, 0.f, 0.f, 0.f);
  __syncthreads();
  for (int j = t; j < 1568; j += 256) {
    int p = j >> 3, c4 = j & 7;
    int ihp = p / 14 + 1, iwp = p % 14 + 1;
    int chunk = (c4 * 16 + ihp) * 16 + (iwp & 1) * 8 + (iwp >> 1);
    xs4[chunk] = *(const float4*)(h1 + n0 * 6272 + p * 32 + c4 * 4);
    xs4[2049 + chunk] = *(const float4*)(h1 + (n0 + 1) * 6272 + p * 32 + c4 * 4);
  }
  __syncthreads();
  int l = t & 63;
  int co0 = __builtin_amdgcn_readfirstlane((t >> 6) * 16);
  int img = l >> 5, pt = l & 31;
  int oh0 = pt >> 3, ow = pt & 7;
  int imgoff = img * 2049;
  bool v0 = (ow < 7);
  bool v1 = (ow < 7) && (oh0 + 4 < 7);
  float4 A0[4], A1[4];
#pragma unroll
  for (int g = 0; g < 4; ++g) { A0[g] = make_float4(0.f, 0.f, 0.f, 0.f); A1[g] = A0[g]; }
#pragma unroll 1
  for (int kk = 0; kk < 16; ++kk) {
    int kh = kk >> 2, kw = kk & 3;
    int cc = 2 * ow + kw; if (cc > 15) cc = 15;
    int off = (cc & 1) * 8 + (cc >> 1);
    int rc0 = 2 * oh0 + kh;
    int rc1 = rc0 + 8; if (rc1 > 15) rc1 = 15;
    int b0 = imgoff + rc0 * 16 + off;
    int b1 = imgoff + rc1 * 16 + off;
    int wb = __builtin_amdgcn_readfirstlane(kk * 2048 + co0);
#pragma unroll 2
    for (int c4 = 0; c4 < 8; ++c4) {
      float4 x0 = xs4[b0 + c4 * 256];
      float4 x1 = xs4[b1 + c4 * 256];
      float xa0[4] = {x0.x, x0.y, x0.z, x0.w};
      float xa1[4] = {x1.x, x1.y, x1.z, x1.w};
      const float* wk = w2 + wb + c4 * 256;
#pragma unroll
      for (int j = 0; j < 4; ++j) {
#pragma unroll
        for (int g = 0; g < 4; ++g) {
          float4 wv4;
          wv4.x = wk[j * 64 + g * 4 + 0]; wv4.y = wk[j * 64 + g * 4 + 1];
          wv4.z = wk[j * 64 + g * 4 + 2]; wv4.w = wk[j * 64 + g * 4 + 3];
          A0[g] = f4fma(xa0[j], wv4, A0[g]);
          A1[g] = f4fma(xa1[j], wv4, A1[g]);
        }
      }
    }
  }
  float4 bias[4];
#pragma unroll
  for (int g = 0; g < 4; ++g) bias[g] = *(const float4*)&b2[co0 + g * 4];
  if (v0) {
    size_t ob = ((n0 + img) * 49 + oh0 * 7 + ow) * 64 + co0;
#pragma unroll
    for (int g = 0; g < 4; ++g)
      *(float4*)&h2[ob + g * 4] = f4relu(f4addrn(A0[g], bias[g]));
  }
  if (v1) {
    size_t ob = ((n0 + img) * 49 + (oh0 + 4) * 7 + ow) * 64 + co0;
#pragma unroll
    for (int g = 0; g < 4; ++g)
      *(float4*)&h2[ob + g * 4] = f4relu(f4addrn(A1[g], bias[g]));
  }
}

// ---- K_pw: 1x1 conv 64->64, bias-after (no act). NHWC ----------------------
__global__ __launch_bounds__(256) void k_pw(const float* __restrict__ xin,
                                            const float* __restrict__ w,     // [ci][co]
                                            const float* __restrict__ bias,
                                            float* __restrict__ yout) {
  __shared__ float tile[256 * 65];
  int t = threadIdx.x;
  long m0 = (long)blockIdx.x * 256;
  for (int j = t; j < 16384; j += 256) tile[(j >> 6) * 65 + (j & 63)] = xin[m0 * 64 + j];
  __syncthreads();
  float xr[64];
#pragma unroll
  for (int ci = 0; ci < 64; ++ci) xr[ci] = tile[t * 65 + ci];
  for (int g = 0; g < 4; ++g) {
    float4 z4 = make_float4(0.f, 0.f, 0.f, 0.f);
    float4 a0 = z4, a1 = z4, a2 = z4, a3 = z4;
#pragma unroll
    for (int ci = 0; ci < 64; ++ci) {
      float xv = xr[ci];
      const float* wr = &w[ci * 64 + g * 16];
      a0 = f4fma(xv, *(const float4*)&wr[0], a0);
      a1 = f4fma(xv, *(const float4*)&wr[4], a1);
      a2 = f4fma(xv, *(const float4*)&wr[8], a2);
      a3 = f4fma(xv, *(const float4*)&wr[12], a3);
    }
    a0 = f4addrn(a0, *(const float4*)&bias[g * 16 + 0]);
    a1 = f4addrn(a1, *(const float4*)&bias[g * 16 + 4]);
    a2 = f4addrn(a2, *(const float4*)&bias[g * 16 + 8]);
    a3 = f4addrn(a3, *(const float4*)&bias[g * 16 + 12]);
    float* dst = &tile[t * 65 + g * 16];
    dst[0] = a0.x; dst[1] = a0.y; dst[2] = a0.z; dst[3] = a0.w;
    dst[4] = a1.x; dst[5] = a1.y; dst[6] = a1.z; dst[7] = a1.w;
    dst[8] = a2.x; dst[9] = a2.y; dst[10] = a2.z; dst[11] = a2.w;
    dst[12] = a3.x; dst[13] = a3.y; dst[14] = a3.z; dst[15] = a3.w;
  }
  __syncthreads();
  for (int j = t; j < 16384; j += 256) yout[m0 * 64 + j] = tile[(j >> 6) * 65 + (j & 63)];
}

// ---- K4: VQ. z NHWC -> idx, z NCHW, z_q NCHW, zq NHWC, loss ----------------
// R7: distance loop k-unrolled x4 (4 independent chains); LDS staging kept.
__global__ __launch_bounds__(256) void k4_vq(const float* __restrict__ zin,
                                             const float* __restrict__ cb,
                                             const float* __restrict__ cn,
                                             float* __restrict__ zq_nhwc,
                                             float* __restrict__ outz,
                                             float* __restrict__ outzq,
                                             float* __restrict__ outidx,
                                             float* __restrict__ loss) {
  __shared__ float tile[256 * 65];
  __shared__ float red[4];
  int t = threadIdx.x;
  long m0 = (long)blockIdx.x * 256;
  for (int j = t; j < 16384; j += 256) tile[(j >> 6) * 65 + (j & 63)] = zin[m0 * 64 + j];
  __syncthreads();
  float zr[64];
#pragma unroll
  for (int ci = 0; ci < 64; ++ci) zr[ci] = tile[t * 65 + ci];
  unsigned m = (unsigned)(m0 + t);
  unsigned n = m / 49u, sp = m % 49u;
  float* zob = outz + (size_t)n * 3136 + sp;
#pragma unroll
  for (int ci = 0; ci < 64; ++ci) zob[ci * 49] = zr[ci];
  // np-exact argmin: dist = fl( fl(SZ + SC_k) - 2*dot ), first-min-wins.
  // k unrolled x4: 4 independent per-code chains (per-code order unchanged).
  float sz = np_sumsq64(zr);
  float minv = 3.4e38f; int mini = 0;
#pragma unroll 1
  for (int k = 0; k < 512; k += 4) {
    const float* cp = cb + (size_t)k * 64;
    float d0_ = 0.f, d1_ = 0.f, d2_ = 0.f, d3_ = 0.f;
#pragma unroll
    for (int ci = 0; ci < 64; ci += 4) {
      float4 a = *(const float4*)(cp + ci);
      float4 b = *(const float4*)(cp + 64 + ci);
      float4 c = *(const float4*)(cp + 128 + ci);
      float4 e = *(const float4*)(cp + 192 + ci);
      d0_ = fmaf(zr[ci], a.x, d0_); d0_ = fmaf(zr[ci + 1], a.y, d0_);
      d0_ = fmaf(zr[ci + 2], a.z, d0_); d0_ = fmaf(zr[ci + 3], a.w, d0_);
      d1_ = fmaf(zr[ci], b.x, d1_); d1_ = fmaf(zr[ci + 1], b.y, d1_);
      d1_ = fmaf(zr[ci + 2], b.z, d1_); d1_ = fmaf(zr[ci + 3], b.w, d1_);
      d2_ = fmaf(zr[ci], c.x, d2_); d2_ = fmaf(zr[ci + 1], c.y, d2_);
      d2_ = fmaf(zr[ci + 2], c.z, d2_); d2_ = fmaf(zr[ci + 3], c.w, d2_);
      d3_ = fmaf(zr[ci], e.x, d3_); d3_ = fmaf(zr[ci + 1], e.y, d3_);
      d3_ = fmaf(zr[ci + 2], e.z, d3_); d3_ = fmaf(zr[ci + 3], e.w, d3_);
    }
    float q0 = __fsub_rn(__fadd_rn(sz, cn[k + 0]), __fmul_rn(2.f, d0_));
    float q1 = __fsub_rn(__fadd_rn(sz, cn[k + 1]), __fmul_rn(2.f, d1_));
    float q2 = __fsub_rn(__fadd_rn(sz, cn[k + 2]), __fmul_rn(2.f, d2_));
    float q3 = __fsub_rn(__fadd_rn(sz, cn[k + 3]), __fmul_rn(2.f, d3_));
    if (q0 < minv) { minv = q0; mini = k; }
    if (q1 < minv) { minv = q1; mini = k + 1; }
    if (q2 < minv) { minv = q2; mini = k + 2; }
    if (q3 < minv) { minv = q3; mini = k + 3; }
  }
  outidx[m] = (float)mini;
  float* qob = outzq + (size_t)n * 3136 + sp;
  float lsum = 0.f;
#pragma unroll
  for (int ci = 0; ci < 64; ci += 4) {
    float4 q4 = *(const float4*)&cb[mini * 64 + ci];
    float* dst = &tile[t * 65 + ci];
    dst[0] = q4.x; dst[1] = q4.y; dst[2] = q4.z; dst[3] = q4.w;
    qob[(ci + 0) * 49] = q4.x; qob[(ci + 1) * 49] = q4.y;
    qob[(ci + 2) * 49] = q4.z; qob[(ci + 3) * 49] = q4.w;
    float e0 = q4.x - zr[ci + 0], e1 = q4.y - zr[ci + 1];
    float e2 = q4.z - zr[ci + 2], e3 = q4.w - zr[ci + 3];
    lsum = fmaf(e0, e0, lsum); lsum = fmaf(e1, e1, lsum);
    lsum = fmaf(e2, e2, lsum); lsum = fmaf(e3, e3, lsum);
  }
#pragma unroll
  for (int off = 32; off > 0; off >>= 1) lsum += __shfl_down(lsum, off);
  int wid = t >> 6, lane = t & 63;
  if (lane == 0) red[wid] = lsum;
  __syncthreads();
  if (t == 0) atomicAdd(loss, red[0] + red[1] + red[2] + red[3]);
  for (int j = t; j < 16384; j += 256) zq_nhwc[m0 * 64 + j] = tile[(j >> 6) * 65 + (j & 63)];
}

// ---- K4b: finalize loss ----------------------------------------------------
__global__ __launch_bounds__(64) void k_lossfin(const float* __restrict__ loss,
                                                float* __restrict__ out) {
  if (threadIdx.x == 0) out[0] = loss[0] * (1.25f / 12845056.f);
}

// ---- K6: deconv1 4x4 s2 p2 (lhs_dilation), 64->32, ReLU. NHWC --------------
// Wave = phase (ra=oh&1, rb=ow&1); x staged ONCE in padded grid
// [c4:16][row:9][col:9] f4 chunks (img stride 1297). Weights via s_load.
// Thread: 2 positions x 32 co. K-loop barrier-free, no per-phase restage.
__global__ __launch_bounds__(256) void k6_deconv1(const float* __restrict__ d0,
                                                  const float* __restrict__ dw1,
                                                  const float* __restrict__ db1,
                                                  float* __restrict__ d1) {
  __shared__ float4 xs4[2 * 1297];
  int nb = blockIdx.x, t = threadIdx.x;
  size_t n0 = (size_t)nb * 2;
  for (int j = t; j < 2594; j += 256) xs4[j] = make_float4(0.f, 0.f, 0.f, 0.f);
  __syncthreads();
  for (int j = t; j < 784; j += 256) {
    int p = j >> 4, c4 = j & 15;
    int chunk = c4 * 81 + (p / 7 + 1) * 9 + (p % 7 + 1);
    xs4[chunk] = *(const float4*)(d0 + n0 * 3136 + p * 64 + c4 * 4);
    xs4[1297 + chunk] = *(const float4*)(d0 + (n0 + 1) * 3136 + p * 64 + c4 * 4);
  }
  __syncthreads();
  int l = t & 63;
  int ph = __builtin_amdgcn_readfirstlane(t >> 6);
  int ra = ph >> 1, rb = ph & 1;
  int img = l >> 5, pt = l & 31;
  bool v1 = (pt + 32 < 49);
  int p1 = v1 ? pt + 32 : 48;
  int mh0 = pt / 7, mw0 = pt % 7;
  int mh1 = p1 / 7, mw1 = p1 % 7;
  int imgoff = img * 1297;
  float4 A0[8], A1[8];
#pragma unroll
  for (int g = 0; g < 8; ++g) { A0[g] = make_float4(0.f, 0.f, 0.f, 0.f); A1[g] = A0[g]; }
#pragma unroll 1
  for (int tap = 0; tap < 4; ++tap) {
    int th = tap >> 1, tw = tap & 1;
    int kh = 2 * th + ra, kw = 2 * tw + rb;
    int b0 = imgoff + (mh0 + th + ra) * 9 + (mw0 + tw + rb);
    int b1 = imgoff + (mh1 + th + ra) * 9 + (mw1 + tw + rb);
    int wb = __builtin_amdgcn_readfirstlane((kh * 4 + kw) * 2048);
#pragma unroll 1
    for (int c4 = 0; c4 < 16; ++c4) {
      float4 x0 = xs4[b0 + c4 * 81];
      float4 x1 = xs4[b1 + c4 * 81];
      float xa0[4] = {x0.x, x0.y, x0.z, x0.w};
      float xa1[4] = {x1.x, x1.y, x1.z, x1.w};
      const float* wk = dw1 + wb + c4 * 128;
#pragma unroll
      for (int j = 0; j < 4; ++j) {
#pragma unroll
        for (int g = 0; g < 8; ++g) {
          float4 wv4;
          wv4.x = wk[j * 32 + g * 4 + 0]; wv4.y = wk[j * 32 + g * 4 + 1];
          wv4.z = wk[j * 32 + g * 4 + 2]; wv4.w = wk[j * 32 + g * 4 + 3];
          A0[g] = f4fma(xa0[j], wv4, A0[g]);
          A1[g] = f4fma(xa1[j], wv4, A1[g]);
        }
      }
    }
  }
  int oh0 = 2 * mh0 + ra, ow0 = 2 * mw0 + rb;
  size_t ob0 = ((n0 + img) * 196 + (size_t)(oh0 * 14 + ow0)) * 32;
#pragma unroll
  for (int g = 0; g < 8; ++g) {
    float4 bg = *(const float4*)&db1[g * 4];
    *(float4*)&d1[ob0 + g * 4] = f4relu(f4addrn(A0[g], bg));
  }
  if (v1) {
    int oh1 = 2 * mh1 + ra, ow1 = 2 * mw1 + rb;
    size_t ob1 = ((n0 + img) * 196 + (size_t)(oh1 * 14 + ow1)) * 32;
#pragma unroll
    for (int g = 0; g < 8; ++g) {
      float4 bg = *(const float4*)&db1[g * 4];
      *(float4*)&d1[ob1 + g * 4] = f4relu(f4addrn(A1[g], bg));
    }
  }
}

// ---- K7: deconv2 4x4 s2 p2, 32->1, sigmoid -> recon NCHW -------------------
__global__ __launch_bounds__(256) void k7_deconv2(const float* __restrict__ d1,
                                                  const float* __restrict__ dw2,
                                                  const float* __restrict__ db2,
                                                  float* __restrict__ recon) {
  __shared__ float xs[196 * 36];
  __shared__ float wl[512];
  int n = blockIdx.x, t = threadIdx.x;
  for (int j = t; j < 6272; j += 256) xs[(j >> 5) * 36 + (j & 31)] = d1[(size_t)n * 6272 + j];
  for (int j = t; j < 512; j += 256) wl[j] = dw2[j];
  __syncthreads();
  float bias = db2[0];
  for (int j = t; j < 392; j += 256) {
    int ra = j / 196, rem = j % 196;
    int mh = rem / 14, mw = rem % 14;
    float acc0 = bias, acc1 = bias;
    bool vm = (mw >= 1), vp = (mw + 1 < 14);
#pragma unroll
    for (int th = 0; th < 2; ++th) {
      int ih = mh + th - 1 + ra;
      if (ih < 0 || ih >= 14) continue;
      int kh = 2 * th + ra;
#pragma unroll
      for (int ci = 0; ci < 32; ci += 4) {
        float4 z4 = make_float4(0.f, 0.f, 0.f, 0.f);
        float4 xm = vm ? *(float4*)&xs[(ih * 14 + mw - 1) * 36 + ci] : z4;
        float4 x0 = *(float4*)&xs[(ih * 14 + mw) * 36 + ci];
        float4 xp = vp ? *(float4*)&xs[(ih * 14 + mw + 1) * 36 + ci] : z4;
        float4 wk0 = *(float4*)&wl[(kh * 4 + 0) * 32 + ci];
        float4 wk1 = *(float4*)&wl[(kh * 4 + 1) * 32 + ci];
        float4 wk2 = *(float4*)&wl[(kh * 4 + 2) * 32 + ci];
        float4 wk3 = *(float4*)&wl[(kh * 4 + 3) * 32 + ci];
        acc0 = fmaf(xm.x, wk0.x, acc0); acc0 = fmaf(xm.y, wk0.y, acc0);
        acc0 = fmaf(xm.z, wk0.z, acc0); acc0 = fmaf(xm.w, wk0.w, acc0);
        acc0 = fmaf(x0.x, wk2.x, acc0); acc0 = fmaf(x0.y, wk2.y, acc0);
        acc0 = fmaf(x0.z, wk2.z, acc0); acc0 = fmaf(x0.w, wk2.w, acc0);
        acc1 = fmaf(x0.x, wk1.x, acc1); acc1 = fmaf(x0.y, wk1.y, acc1);
        acc1 = fmaf(x0.z, wk1.z, acc1); acc1 = fmaf(x0.w, wk1.w, acc1);
        acc1 = fmaf(xp.x, wk3.x, acc1); acc1 = fmaf(xp.y, wk3.y, acc1);
        acc1 = fmaf(xp.z, wk3.z, acc1); acc1 = fmaf(xp.w, wk3.w, acc1);
      }
    }
    float r0 = 1.f / (1.f + __expf(-acc0));
    float r1 = 1.f / (1.f + __expf(-acc1));
    int oh = 2 * mh + ra;
    *(float2*)&recon[(size_t)n * 784 + oh * 28 + 2 * mw] = make_float2(r0, r1);
  }
}

extern "C" void kernel_launch(void* const* d_in, const int* in_sizes, int n_in,
                              void* d_out, int out_size, void* d_ws, size_t ws_size,
                              hipStream_t stream) {
  const float* x   = (const float*)d_in[0];
  const float* w1  = (const float*)d_in[1];
  const float* b1  = (const float*)d_in[2];
  const float* w2  = (const float*)d_in[3];
  const float* b2  = (const float*)d_in[4];
  const float* w3  = (const float*)d_in[5];
  const float* b3  = (const float*)d_in[6];
  const float* cb  = (const float*)d_in[7];
  const float* dw0 = (const float*)d_in[8];
  const float* db0 = (const float*)d_in[9];
  const float* dw1 = (const float*)d_in[10];
  const float* db1 = (const float*)d_in[11];
  const float* dw2 = (const float*)d_in[12];
  const float* db2 = (const float*)d_in[13];
  float* out = (float*)d_out;
  float* ws  = (float*)d_ws;

  float* h1   = ws;                 // 25,690,112 (reused as d1)
  float* h2   = ws + 25690112;      // 12,845,056 (reused as zq_nhwc)
  float* zb   = ws + 38535168;      // 12,845,056 z_nhwc (reused as d0)
  float* cn   = ws + 51380224;      // 512
  float* loss = ws + 51380736;      // 1

  float* recon   = out;
  float* zout    = out + 3211264;
  float* zqout   = out + 16056320;
  float* lossout = out + 28901376;
  float* idxout  = out + 28901377;

  k0_init<<<1, 256, 0, stream>>>(cb, cn, loss);
  k1_conv1<<<NB, 256, 0, stream>>>(x, w1, b1, h1);
  k2_conv2<<<NB / 2, 256, 0, stream>>>(h1, w2, b2, h2);
  k_pw<<<784, 256, 0, stream>>>(h2, w3, b3, zb);                 // z = h2 @ w3 + b3
  k4_vq<<<784, 256, 0, stream>>>(zb, cb, cn, h2, zout, zqout, idxout, loss);
  k_lossfin<<<1, 64, 0, stream>>>(loss, lossout);
  k_pw<<<784, 256, 0, stream>>>(h2, dw0, db0, zb);               // d0 = zq @ dw0 + db0
  k6_deconv1<<<NB / 2, 256, 0, stream>>>(zb, dw1, db1, h1);
  k7_deconv2<<<NB, 256, 0, stream>>>(h1, dw2, db2, recon);
}

// Round 8
// 1208.150 us; speedup vs baseline: 1.9172x; 1.0764x over previous
//
#include <hip/hip_runtime.h>

// ============================================================================
// VQ-VAE forward, MI355X fp32. Internal layout NHWC; outputs NCHW.
// B=4096. x(4096,1,28,28) -> h1(4096,14,14,32) -> h2(4096,7,7,64)
//   -> z -> VQ(512 codes, D=64) -> d0 -> d1(4096,14,14,32) -> recon.
// VQ argmin reproduces np fp32 semantics exactly:
//   dist = fl( fl(SZ + SC_k) - 2*dot(z,c_k) ), SZ/SC via numpy pairwise-8,
//   dot via sequential-K fma (BLAS order), first-min-wins tie break.
// R2: unrolled tap loop -> 256-VGPR cap -> scratch spill -> 12 GB HBM.
// R3: barrier-per-slice weight staging -> global latency on critical path.
// R4: k2/k6 were LDS-read bound -> s_load weights + polyphase LDS x + big
//   register tiles, barrier-free K loops.
// R6 (REVERTED): per-thread-contiguous global access (256B wave stride) is
//   catastrophic: 64 line-req/instr, 2x write amp. Stage coalesced via LDS.
// R7 lesson: k-unroll x4 on global-cb loop didn't help -> NOT fma-latency
//   bound; bound by streaming 128KB cb from L2 per k-iter (L1 too small).
// R8: cb in LDS chunks (16KB x8), 2 points/thread + k-unroll x2 = 4 chains,
//   256 fma : 32 ds_read_b128. LDS union (z tile / cb+cn) = 33.3KB.
// Workspace (floats): h1/d1 @0 (25,690,112) | h2/zq @25,690,112 (12,845,056)
//   | z/d0 @38,535,168 (12,845,056) | cn @51,380,224 (512) | loss @51,380,736
// Out (floats): recon@0, z@3,211,264, z_q@16,056,320, loss@28,901,376,
//   idx@28,901,377 (200,704)
// ============================================================================

#define NB 4096

__device__ __forceinline__ float4 f4fma(float s, float4 w, float4 a) {
  a.x = fmaf(s, w.x, a.x); a.y = fmaf(s, w.y, a.y);
  a.z = fmaf(s, w.z, a.z); a.w = fmaf(s, w.w, a.w);
  return a;
}
__device__ __forceinline__ float4 f4relu(float4 a) {
  a.x = fmaxf(a.x, 0.f); a.y = fmaxf(a.y, 0.f);
  a.z = fmaxf(a.z, 0.f); a.w = fmaxf(a.w, 0.f);
  return a;
}
__device__ __forceinline__ float4 f4addrn(float4 a, float4 b) {
  a.x = __fadd_rn(a.x, b.x); a.y = __fadd_rn(a.y, b.y);
  a.z = __fadd_rn(a.z, b.z); a.w = __fadd_rn(a.w, b.w);
  return a;
}

// numpy pairwise-8 sum of squares over 64 contiguous values
__device__ __forceinline__ float np_sumsq64(const float* v) {
  float r[8];
#pragma unroll
  for (int j = 0; j < 8; ++j) r[j] = __fmul_rn(v[j], v[j]);
#pragma unroll
  for (int i = 8; i < 64; i += 8)
#pragma unroll
    for (int j = 0; j < 8; ++j) r[j] = __fadd_rn(r[j], __fmul_rn(v[i + j], v[i + j]));
  return __fadd_rn(__fadd_rn(__fadd_rn(r[0], r[1]), __fadd_rn(r[2], r[3])),
                   __fadd_rn(__fadd_rn(r[4], r[5]), __fadd_rn(r[6], r[7])));
}

// ---- K0: codebook norms (numpy-order) + zero loss accumulator --------------
__global__ __launch_bounds__(256) void k0_init(const float* __restrict__ cb,
                                               float* __restrict__ cn,
                                               float* __restrict__ loss) {
  int t = threadIdx.x;
  if (t == 0) *loss = 0.f;
  for (int k = t; k < 512; k += 256) cn[k] = np_sumsq64(&cb[k * 64]);
}

// ---- K1: conv1 4x4 s2 p1, 1->32, bias-after, ReLU. out h1 NHWC -------------
__global__ __launch_bounds__(256) void k1_conv1(const float* __restrict__ x,
                                                const float* __restrict__ w1,
                                                const float* __restrict__ b1,
                                                float* __restrict__ h1) {
  __shared__ float xs[784];
  __shared__ float wl[512];
  __shared__ float bs[32];
  int n = blockIdx.x, t = threadIdx.x;
  for (int j = t; j < 784; j += 256) xs[j] = x[n * 784 + j];
  for (int j = t; j < 512; j += 256) wl[j] = w1[j];
  if (t < 32) bs[t] = b1[t];
  __syncthreads();
  int c = t & 31, pg = t >> 5;
  for (int s = pg; s < 196; s += 8) {
    int oh = s / 14, ow = s % 14;
    float acc = 0.f;
#pragma unroll
    for (int kh = 0; kh < 4; ++kh) {
      int ih = 2 * oh - 1 + kh;
      if (ih < 0 || ih >= 28) continue;
#pragma unroll
      for (int kw = 0; kw < 4; ++kw) {
        int iw = 2 * ow - 1 + kw;
        if (iw < 0 || iw >= 28) continue;
        acc = fmaf(xs[ih * 28 + iw], wl[(kh * 4 + kw) * 32 + c], acc);
      }
    }
    acc = __fadd_rn(acc, bs[c]);
    h1[(n * 196 + s) * 32 + c] = fmaxf(acc, 0.f);
  }
}

// ---- K2: conv2 4x4 s2 p1, 32->64, bias-after, ReLU. NHWC -------------------
__global__ __launch_bounds__(256) void k2_conv2(const float* __restrict__ h1,
                                                const float* __restrict__ w2,
                                                const float* __restrict__ b2,
                                                float* __restrict__ h2) {
  __shared__ float4 xs4[2 * 2049];
  int nb = blockIdx.x, t = threadIdx.x;
  size_t n0 = (size_t)nb * 2;
  for (int j = t; j < 4098; j += 256) xs4[j] = make_float4(0.f, 0.f, 0.f, 0.f);
  __syncthreads();
  for (int j = t; j < 1568; j += 256) {
    int p = j >> 3, c4 = j & 7;
    int ihp = p / 14 + 1, iwp = p % 14 + 1;
    int chunk = (c4 * 16 + ihp) * 16 + (iwp & 1) * 8 + (iwp >> 1);
    xs4[chunk] = *(const float4*)(h1 + n0 * 6272 + p * 32 + c4 * 4);
    xs4[2049 + chunk] = *(const float4*)(h1 + (n0 + 1) * 6272 + p * 32 + c4 * 4);
  }
  __syncthreads();
  int l = t & 63;
  int co0 = __builtin_amdgcn_readfirstlane((t >> 6) * 16);
  int img = l >> 5, pt = l & 31;
  int oh0 = pt >> 3, ow = pt & 7;
  int imgoff = img * 2049;
  bool v0 = (ow < 7);
  bool v1 = (ow < 7) && (oh0 + 4 < 7);
  float4 A0[4], A1[4];
#pragma unroll
  for (int g = 0; g < 4; ++g) { A0[g] = make_float4(0.f, 0.f, 0.f, 0.f); A1[g] = A0[g]; }
#pragma unroll 1
  for (int kk = 0; kk < 16; ++kk) {
    int kh = kk >> 2, kw = kk & 3;
    int cc = 2 * ow + kw; if (cc > 15) cc = 15;
    int off = (cc & 1) * 8 + (cc >> 1);
    int rc0 = 2 * oh0 + kh;
    int rc1 = rc0 + 8; if (rc1 > 15) rc1 = 15;
    int b0 = imgoff + rc0 * 16 + off;
    int b1 = imgoff + rc1 * 16 + off;
    int wb = __builtin_amdgcn_readfirstlane(kk * 2048 + co0);
#pragma unroll 2
    for (int c4 = 0; c4 < 8; ++c4) {
      float4 x0 = xs4[b0 + c4 * 256];
      float4 x1 = xs4[b1 + c4 * 256];
      float xa0[4] = {x0.x, x0.y, x0.z, x0.w};
      float xa1[4] = {x1.x, x1.y, x1.z, x1.w};
      const float* wk = w2 + wb + c4 * 256;
#pragma unroll
      for (int j = 0; j < 4; ++j) {
#pragma unroll
        for (int g = 0; g < 4; ++g) {
          float4 wv4;
          wv4.x = wk[j * 64 + g * 4 + 0]; wv4.y = wk[j * 64 + g * 4 + 1];
          wv4.z = wk[j * 64 + g * 4 + 2]; wv4.w = wk[j * 64 + g * 4 + 3];
          A0[g] = f4fma(xa0[j], wv4, A0[g]);
          A1[g] = f4fma(xa1[j], wv4, A1[g]);
        }
      }
    }
  }
  float4 bias[4];
#pragma unroll
  for (int g = 0; g < 4; ++g) bias[g] = *(const float4*)&b2[co0 + g * 4];
  if (v0) {
    size_t ob = ((n0 + img) * 49 + oh0 * 7 + ow) * 64 + co0;
#pragma unroll
    for (int g = 0; g < 4; ++g)
      *(float4*)&h2[ob + g * 4] = f4relu(f4addrn(A0[g], bias[g]));
  }
  if (v1) {
    size_t ob = ((n0 + img) * 49 + (oh0 + 4) * 7 + ow) * 64 + co0;
#pragma unroll
    for (int g = 0; g < 4; ++g)
      *(float4*)&h2[ob + g * 4] = f4relu(f4addrn(A1[g], bias[g]));
  }
}

// ---- K_pw: 1x1 conv 64->64, bias-after (no act). NHWC ----------------------
__global__ __launch_bounds__(256) void k_pw(const float* __restrict__ xin,
                                            const float* __restrict__ w,     // [ci][co]
                                            const float* __restrict__ bias,
                                            float* __restrict__ yout) {
  __shared__ float tile[256 * 65];
  int t = threadIdx.x;
  long m0 = (long)blockIdx.x * 256;
  for (int j = t; j < 16384; j += 256) tile[(j >> 6) * 65 + (j & 63)] = xin[m0 * 64 + j];
  __syncthreads();
  float xr[64];
#pragma unroll
  for (int ci = 0; ci < 64; ++ci) xr[ci] = tile[t * 65 + ci];
  for (int g = 0; g < 4; ++g) {
    float4 z4 = make_float4(0.f, 0.f, 0.f, 0.f);
    float4 a0 = z4, a1 = z4, a2 = z4, a3 = z4;
#pragma unroll
    for (int ci = 0; ci < 64; ++ci) {
      float xv = xr[ci];
      const float* wr = &w[ci * 64 + g * 16];
      a0 = f4fma(xv, *(const float4*)&wr[0], a0);
      a1 = f4fma(xv, *(const float4*)&wr[4], a1);
      a2 = f4fma(xv, *(const float4*)&wr[8], a2);
      a3 = f4fma(xv, *(const float4*)&wr[12], a3);
    }
    a0 = f4addrn(a0, *(const float4*)&bias[g * 16 + 0]);
    a1 = f4addrn(a1, *(const float4*)&bias[g * 16 + 4]);
    a2 = f4addrn(a2, *(const float4*)&bias[g * 16 + 8]);
    a3 = f4addrn(a3, *(const float4*)&bias[g * 16 + 12]);
    float* dst = &tile[t * 65 + g * 16];
    dst[0] = a0.x; dst[1] = a0.y; dst[2] = a0.z; dst[3] = a0.w;
    dst[4] = a1.x; dst[5] = a1.y; dst[6] = a1.z; dst[7] = a1.w;
    dst[8] = a2.x; dst[9] = a2.y; dst[10] = a2.z; dst[11] = a2.w;
    dst[12] = a3.x; dst[13] = a3.y; dst[14] = a3.z; dst[15] = a3.w;
  }
  __syncthreads();
  for (int j = t; j < 16384; j += 256) yout[m0 * 64 + j] = tile[(j >> 6) * 65 + (j & 63)];
}

// ---- K4: VQ. 512 points/block (2/thread), cb in LDS chunks -----------------
// LDS union: z-stage tile 128x65 | cbs[4096] + cns[512]. k-unroll x2 ->
// 4 independent chains; np-exact per-code order and k-ascending compares.
__global__ __launch_bounds__(256) void k4_vq(const float* __restrict__ zin,
                                             const float* __restrict__ cb,
                                             const float* __restrict__ cn,
                                             float* __restrict__ zq_nhwc,
                                             float* __restrict__ outz,
                                             float* __restrict__ outzq,
                                             float* __restrict__ outidx,
                                             float* __restrict__ loss) {
  __shared__ float lds[8320];   // 128*65 tile  |  cbs[0..4096) + cns[4096..4608)
  __shared__ float red[4];
  int t = threadIdx.x;
  size_t m0 = (size_t)blockIdx.x * 512;
  float zrA[64], zrB[64];

#define K4_STAGE_IN(S, ZR)                                                    \
  {                                                                           \
    __syncthreads();                                                          \
    const float* src = zin + (m0 + (S) * 128) * 64;                           \
    for (int j4 = t; j4 < 2048; j4 += 256) {                                  \
      int row = j4 >> 4, col = (j4 & 15) * 4;                                 \
      *(float4*)&lds[row * 65 + col] = *(const float4*)(src + j4 * 4);        \
    }                                                                         \
    __syncthreads();                                                          \
    if ((t >> 7) == ((S) & 1)) {                                              \
      int r = t & 127;                                                        \
      _Pragma("unroll")                                                       \
      for (int ci = 0; ci < 64; ci += 4) {                                    \
        float4 v = *(float4*)&lds[r * 65 + ci];                               \
        ZR[ci] = v.x; ZR[ci + 1] = v.y; ZR[ci + 2] = v.z; ZR[ci + 3] = v.w;   \
      }                                                                       \
    }                                                                         \
  }

  K4_STAGE_IN(0, zrA)
  K4_STAGE_IN(1, zrA)
  K4_STAGE_IN(2, zrB)
  K4_STAGE_IN(3, zrB)

  float szA = np_sumsq64(zrA), szB = np_sumsq64(zrB);
  float minA = 3.4e38f, minB = 3.4e38f;
  int miA = 0, miB = 0;
#pragma unroll 1
  for (int ch = 0; ch < 8; ++ch) {
    __syncthreads();
    for (int j = t; j < 4096; j += 256) lds[j] = cb[ch * 4096 + j];
    if (ch == 0)
      for (int j = t; j < 512; j += 256) lds[4096 + j] = cn[j];
    __syncthreads();
#pragma unroll 1
    for (int k = 0; k < 64; k += 2) {
      const float* r0 = &lds[k * 64];
      const float* r1 = r0 + 64;
      float dA0 = 0.f, dA1 = 0.f, dB0 = 0.f, dB1 = 0.f;
#pragma unroll
      for (int ci = 0; ci < 64; ci += 4) {
        float4 c0 = *(const float4*)(r0 + ci);
        float4 c1 = *(const float4*)(r1 + ci);
        dA0 = fmaf(zrA[ci], c0.x, dA0); dA0 = fmaf(zrA[ci + 1], c0.y, dA0);
        dA0 = fmaf(zrA[ci + 2], c0.z, dA0); dA0 = fmaf(zrA[ci + 3], c0.w, dA0);
        dB0 = fmaf(zrB[ci], c0.x, dB0); dB0 = fmaf(zrB[ci + 1], c0.y, dB0);
        dB0 = fmaf(zrB[ci + 2], c0.z, dB0); dB0 = fmaf(zrB[ci + 3], c0.w, dB0);
        dA1 = fmaf(zrA[ci], c1.x, dA1); dA1 = fmaf(zrA[ci + 1], c1.y, dA1);
        dA1 = fmaf(zrA[ci + 2], c1.z, dA1); dA1 = fmaf(zrA[ci + 3], c1.w, dA1);
        dB1 = fmaf(zrB[ci], c1.x, dB1); dB1 = fmaf(zrB[ci + 1], c1.y, dB1);
        dB1 = fmaf(zrB[ci + 2], c1.z, dB1); dB1 = fmaf(zrB[ci + 3], c1.w, dB1);
      }
      float cn0 = lds[4096 + ch * 64 + k];
      float cn1 = lds[4096 + ch * 64 + k + 1];
      float qA0 = __fsub_rn(__fadd_rn(szA, cn0), __fmul_rn(2.f, dA0));
      float qA1 = __fsub_rn(__fadd_rn(szA, cn1), __fmul_rn(2.f, dA1));
      float qB0 = __fsub_rn(__fadd_rn(szB, cn0), __fmul_rn(2.f, dB0));
      float qB1 = __fsub_rn(__fadd_rn(szB, cn1), __fmul_rn(2.f, dB1));
      int kk = ch * 64 + k;
      if (qA0 < minA) { minA = qA0; miA = kk; }
      if (qA1 < minA) { minA = qA1; miA = kk + 1; }
      if (qB0 < minB) { minB = qB0; miB = kk; }
      if (qB1 < minB) { minB = qB1; miB = kk + 1; }
    }
  }
  // idx + z NCHW scatter (zr still live)
  outidx[m0 + t] = (float)miA;
  outidx[m0 + 256 + t] = (float)miB;
  {
    unsigned mA = (unsigned)(m0 + t), mB = (unsigned)(m0 + 256 + t);
    unsigned nA = mA / 49u, spA = mA % 49u;
    unsigned nB = mB / 49u, spB = mB % 49u;
    float* zoA = outz + (size_t)nA * 3136 + spA;
    float* zoB = outz + (size_t)nB * 3136 + spB;
#pragma unroll
    for (int ci = 0; ci < 64; ++ci) { zoA[ci * 49] = zrA[ci]; zoB[ci * 49] = zrB[ci]; }
  }
  float lsum = 0.f;
#define K4_STAGE_OUT(S, ZR, MI)                                               \
  {                                                                           \
    __syncthreads();                                                          \
    if ((t >> 7) == ((S) & 1)) {                                              \
      int r = t & 127;                                                        \
      unsigned mm = (unsigned)(m0 + (S) * 128 + r);                           \
      unsigned nn = mm / 49u, ss = mm % 49u;                                  \
      float* qo = outzq + (size_t)nn * 3136 + ss;                             \
      const float* qr = cb + (size_t)(MI) * 64;                               \
      _Pragma("unroll")                                                       \
      for (int ci = 0; ci < 64; ci += 4) {                                    \
        float4 q4 = *(const float4*)(qr + ci);                                \
        *(float4*)&lds[r * 65 + ci] = q4;                                     \
        qo[(ci + 0) * 49] = q4.x; qo[(ci + 1) * 49] = q4.y;                   \
        qo[(ci + 2) * 49] = q4.z; qo[(ci + 3) * 49] = q4.w;                   \
        float e0 = q4.x - ZR[ci], e1 = q4.y - ZR[ci + 1];                     \
        float e2 = q4.z - ZR[ci + 2], e3 = q4.w - ZR[ci + 3];                 \
        lsum = fmaf(e0, e0, lsum); lsum = fmaf(e1, e1, lsum);                 \
        lsum = fmaf(e2, e2, lsum); lsum = fmaf(e3, e3, lsum);                 \
      }                                                                       \
    }                                                                         \
    __syncthreads();                                                          \
    float* dstg = zq_nhwc + (m0 + (S) * 128) * 64;                            \
    for (int j4 = t; j4 < 2048; j4 += 256) {                                  \
      int row = j4 >> 4, col = (j4 & 15) * 4;                                 \
      *(float4*)(dstg + j4 * 4) = *(float4*)&lds[row * 65 + col];             \
    }                                                                         \
  }
  K4_STAGE_OUT(0, zrA, miA)
  K4_STAGE_OUT(1, zrA, miA)
  K4_STAGE_OUT(2, zrB, miB)
  K4_STAGE_OUT(3, zrB, miB)
#pragma unroll
  for (int off = 32; off > 0; off >>= 1) lsum += __shfl_down(lsum, off);
  int wid = t >> 6, lane = t & 63;
  if (lane == 0) red[wid] = lsum;
  __syncthreads();
  if (t == 0) atomicAdd(loss, red[0] + red[1] + red[2] + red[3]);
#undef K4_STAGE_IN
#undef K4_STAGE_OUT
}

// ---- K4b: finalize loss ----------------------------------------------------
__global__ __launch_bounds__(64) void k_lossfin(const float* __restrict__ loss,
                                                float* __restrict__ out) {
  if (threadIdx.x == 0) out[0] = loss[0] * (1.25f / 12845056.f);
}

// ---- K6: deconv1 4x4 s2 p2 (lhs_dilation), 64->32, ReLU. NHWC --------------
__global__ __launch_bounds__(256) void k6_deconv1(const float* __restrict__ d0,
                                                  const float* __restrict__ dw1,
                                                  const float* __restrict__ db1,
                                                  float* __restrict__ d1) {
  __shared__ float4 xs4[2 * 1297];
  int nb = blockIdx.x, t = threadIdx.x;
  size_t n0 = (size_t)nb * 2;
  for (int j = t; j < 2594; j += 256) xs4[j] = make_float4(0.f, 0.f, 0.f, 0.f);
  __syncthreads();
  for (int j = t; j < 784; j += 256) {
    int p = j >> 4, c4 = j & 15;
    int chunk = c4 * 81 + (p / 7 + 1) * 9 + (p % 7 + 1);
    xs4[chunk] = *(const float4*)(d0 + n0 * 3136 + p * 64 + c4 * 4);
    xs4[1297 + chunk] = *(const float4*)(d0 + (n0 + 1) * 3136 + p * 64 + c4 * 4);
  }
  __syncthreads();
  int l = t & 63;
  int ph = __builtin_amdgcn_readfirstlane(t >> 6);
  int ra = ph >> 1, rb = ph & 1;
  int img = l >> 5, pt = l & 31;
  bool v1 = (pt + 32 < 49);
  int p1 = v1 ? pt + 32 : 48;
  int mh0 = pt / 7, mw0 = pt % 7;
  int mh1 = p1 / 7, mw1 = p1 % 7;
  int imgoff = img * 1297;
  float4 A0[8], A1[8];
#pragma unroll
  for (int g = 0; g < 8; ++g) { A0[g] = make_float4(0.f, 0.f, 0.f, 0.f); A1[g] = A0[g]; }
#pragma unroll 1
  for (int tap = 0; tap < 4; ++tap) {
    int th = tap >> 1, tw = tap & 1;
    int kh = 2 * th + ra, kw = 2 * tw + rb;
    int b0 = imgoff + (mh0 + th + ra) * 9 + (mw0 + tw + rb);
    int b1 = imgoff + (mh1 + th + ra) * 9 + (mw1 + tw + rb);
    int wb = __builtin_amdgcn_readfirstlane((kh * 4 + kw) * 2048);
#pragma unroll 1
    for (int c4 = 0; c4 < 16; ++c4) {
      float4 x0 = xs4[b0 + c4 * 81];
      float4 x1 = xs4[b1 + c4 * 81];
      float xa0[4] = {x0.x, x0.y, x0.z, x0.w};
      float xa1[4] = {x1.x, x1.y, x1.z, x1.w};
      const float* wk = dw1 + wb + c4 * 128;
#pragma unroll
      for (int j = 0; j < 4; ++j) {
#pragma unroll
        for (int g = 0; g < 8; ++g) {
          float4 wv4;
          wv4.x = wk[j * 32 + g * 4 + 0]; wv4.y = wk[j * 32 + g * 4 + 1];
          wv4.z = wk[j * 32 + g * 4 + 2]; wv4.w = wk[j * 32 + g * 4 + 3];
          A0[g] = f4fma(xa0[j], wv4, A0[g]);
          A1[g] = f4fma(xa1[j], wv4, A1[g]);
        }
      }
    }
  }
  int oh0 = 2 * mh0 + ra, ow0 = 2 * mw0 + rb;
  size_t ob0 = ((n0 + img) * 196 + (size_t)(oh0 * 14 + ow0)) * 32;
#pragma unroll
  for (int g = 0; g < 8; ++g) {
    float4 bg = *(const float4*)&db1[g * 4];
    *(float4*)&d1[ob0 + g * 4] = f4relu(f4addrn(A0[g], bg));
  }
  if (v1) {
    int oh1 = 2 * mh1 + ra, ow1 = 2 * mw1 + rb;
    size_t ob1 = ((n0 + img) * 196 + (size_t)(oh1 * 14 + ow1)) * 32;
#pragma unroll
    for (int g = 0; g < 8; ++g) {
      float4 bg = *(const float4*)&db1[g * 4];
      *(float4*)&d1[ob1 + g * 4] = f4relu(f4addrn(A1[g], bg));
    }
  }
}

// ---- K7: deconv2 4x4 s2 p2, 32->1, sigmoid -> recon NCHW -------------------
__global__ __launch_bounds__(256) void k7_deconv2(const float* __restrict__ d1,
                                                  const float* __restrict__ dw2,
                                                  const float* __restrict__ db2,
                                                  float* __restrict__ recon) {
  __shared__ float xs[196 * 36];
  __shared__ float wl[512];
  int n = blockIdx.x, t = threadIdx.x;
  for (int j = t; j < 6272; j += 256) xs[(j >> 5) * 36 + (j & 31)] = d1[(size_t)n * 6272 + j];
  for (int j = t; j < 512; j += 256) wl[j] = dw2[j];
  __syncthreads();
  float bias = db2[0];
  for (int j = t; j < 392; j += 256) {
    int ra = j / 196, rem = j % 196;
    int mh = rem / 14, mw = rem % 14;
    float acc0 = bias, acc1 = bias;
    bool vm = (mw >= 1), vp = (mw + 1 < 14);
#pragma unroll
    for (int th = 0; th < 2; ++th) {
      int ih = mh + th - 1 + ra;
      if (ih < 0 || ih >= 14) continue;
      int kh = 2 * th + ra;
#pragma unroll
      for (int ci = 0; ci < 32; ci += 4) {
        float4 z4 = make_float4(0.f, 0.f, 0.f, 0.f);
        float4 xm = vm ? *(float4*)&xs[(ih * 14 + mw - 1) * 36 + ci] : z4;
        float4 x0 = *(float4*)&xs[(ih * 14 + mw) * 36 + ci];
        float4 xp = vp ? *(float4*)&xs[(ih * 14 + mw + 1) * 36 + ci] : z4;
        float4 wk0 = *(float4*)&wl[(kh * 4 + 0) * 32 + ci];
        float4 wk1 = *(float4*)&wl[(kh * 4 + 1) * 32 + ci];
        float4 wk2 = *(float4*)&wl[(kh * 4 + 2) * 32 + ci];
        float4 wk3 = *(float4*)&wl[(kh * 4 + 3) * 32 + ci];
        acc0 = fmaf(xm.x, wk0.x, acc0); acc0 = fmaf(xm.y, wk0.y, acc0);
        acc0 = fmaf(xm.z, wk0.z, acc0); acc0 = fmaf(xm.w, wk0.w, acc0);
        acc0 = fmaf(x0.x, wk2.x, acc0); acc0 = fmaf(x0.y, wk2.y, acc0);
        acc0 = fmaf(x0.z, wk2.z, acc0); acc0 = fmaf(x0.w, wk2.w, acc0);
        acc1 = fmaf(x0.x, wk1.x, acc1); acc1 = fmaf(x0.y, wk1.y, acc1);
        acc1 = fmaf(x0.z, wk1.z, acc1); acc1 = fmaf(x0.w, wk1.w, acc1);
        acc1 = fmaf(xp.x, wk3.x, acc1); acc1 = fmaf(xp.y, wk3.y, acc1);
        acc1 = fmaf(xp.z, wk3.z, acc1); acc1 = fmaf(xp.w, wk3.w, acc1);
      }
    }
    float r0 = 1.f / (1.f + __expf(-acc0));
    float r1 = 1.f / (1.f + __expf(-acc1));
    int oh = 2 * mh + ra;
    *(float2*)&recon[(size_t)n * 784 + oh * 28 + 2 * mw] = make_float2(r0, r1);
  }
}

extern "C" void kernel_launch(void* const* d_in, const int* in_sizes, int n_in,
                              void* d_out, int out_size, void* d_ws, size_t ws_size,
                              hipStream_t stream) {
  const float* x   = (const float*)d_in[0];
  const float* w1  = (const float*)d_in[1];
  const float* b1  = (const float*)d_in[2];
  const float* w2  = (const float*)d_in[3];
  const float* b2  = (const float*)d_in[4];
  const float* w3  = (const float*)d_in[5];
  const float* b3  = (const float*)d_in[6];
  const float* cb  = (const float*)d_in[7];
  const float* dw0 = (const float*)d_in[8];
  const float* db0 = (const float*)d_in[9];
  const float* dw1 = (const float*)d_in[10];
  const float* db1 = (const float*)d_in[11];
  const float* dw2 = (const float*)d_in[12];
  const float* db2 = (const float*)d_in[13];
  float* out = (float*)d_out;
  float* ws  = (float*)d_ws;

  float* h1   = ws;                 // 25,690,112 (reused as d1)
  float* h2   = ws + 25690112;      // 12,845,056 (reused as zq_nhwc)
  float* zb   = ws + 38535168;      // 12,845,056 z_nhwc (reused as d0)
  float* cn   = ws + 51380224;      // 512
  float* loss = ws + 51380736;      // 1

  float* recon   = out;
  float* zout    = out + 3211264;
  float* zqout   = out + 16056320;
  float* lossout = out + 28901376;
  float* idxout  = out + 28901377;

  k0_init<<<1, 256, 0, stream>>>(cb, cn, loss);
  k1_conv1<<<NB, 256, 0, stream>>>(x, w1, b1, h1);
  k2_conv2<<<NB / 2, 256, 0, stream>>>(h1, w2, b2, h2);
  k_pw<<<784, 256, 0, stream>>>(h2, w3, b3, zb);                 // z = h2 @ w3 + b3
  k4_vq<<<392, 256, 0, stream>>>(zb, cb, cn, h2, zout, zqout, idxout, loss);
  k_lossfin<<<1, 64, 0, stream>>>(loss, lossout);
  k_pw<<<784, 256, 0, stream>>>(h2, dw0, db0, zb);               // d0 = zq @ dw0 + db0
  k6_deconv1<<<NB / 2, 256, 0, stream>>>(zb, dw1, db1, h1);
  k7_deconv2<<<NB, 256, 0, stream>>>(h1, dw2, db2, recon);
}